// Round 11
// baseline (118.478 us; speedup 1.0000x reference)
//
#include <hip/hip_runtime.h>

// CausalSelfAttention: B=4, T=2048, D=1024, DA=256, fp32 in/out.
// 4 launches: prep -> qkvt (Vt GEMM + QK GEMM) -> scores (bf16 E + partials)
// -> pv_fin (PV GEMM + W finalize). MFMA kernels: 128x128 tiles, 512 threads
// (8 waves 2Mx4N -> 16 waves/CU at 2 blocks/CU), T4 counted-vmcnt 2-buffer
// global_load_lds pipeline, T2 source-swizzled LDS, T5 setprio on MFMA,
// non-temporal stores for the O/W output streams.

typedef short bf16x8 __attribute__((ext_vector_type(8)));   // 8 bf16 in 4 VGPRs
typedef float f32x4  __attribute__((ext_vector_type(4)));
typedef unsigned int  u32x4 __attribute__((ext_vector_type(4)));
typedef unsigned short u16x4 __attribute__((ext_vector_type(4)));

static __device__ __forceinline__ unsigned short f2bf(float f) {
    union { float f; unsigned int u; } v; v.f = f;
    unsigned int u = v.u;
    return (unsigned short)((u + 0x7FFFu + ((u >> 16) & 1u)) >> 16);  // RNE
}
static __device__ __forceinline__ float bf2f(unsigned short h) {
    union { unsigned int u; float f; } v; v.u = ((unsigned int)h) << 16; return v.f;
}

// async global->LDS, 16B per lane; LDS dest must be wave-linear (lane*16).
#define GLL(g, l) __builtin_amdgcn_global_load_lds( \
    (const __attribute__((address_space(1))) void*)(g), \
    (__attribute__((address_space(3))) void*)(l), 16, 0, 0)

#define BAR() __builtin_amdgcn_s_barrier()
#define VM4() asm volatile("s_waitcnt vmcnt(4)" ::: "memory")
#define VM0() asm volatile("s_waitcnt vmcnt(0)" ::: "memory")

// ---- 512-thread pipeline: 128x128 tile, BK=64, 4 GLL/step (2 per matrix) ----

#define STAGE1(AB, LDA, BB, LDB, t, p) { \
    const unsigned short* Ap_ = (AB) + (size_t)(t) * 64; \
    const unsigned short* Bp_ = (BB) + (size_t)(t) * 64; \
    _Pragma("unroll") \
    for (int i_ = 0; i_ < 2; ++i_) { \
        GLL(Ap_ + (size_t)64 * i_ * (LDA), &As[p][srow + 64 * i_][scol]); \
        GLL(Bp_ + (size_t)64 * i_ * (LDB), &Bs[p][srow + 64 * i_][scol]); \
    } }

#define PIPE_MFMA(AB, LDA, BB, LDB, NT) { \
    STAGE1(AB, LDA, BB, LDB, 0, 0); \
    STAGE1(AB, LDA, BB, LDB, 1, 1); \
    for (int t = 0; t < (NT); ++t) { \
        int p = t & 1; \
        if (t + 1 < (NT)) VM4(); else VM0(); \
        BAR(); \
        __builtin_amdgcn_s_setprio(1); \
        _Pragma("unroll") \
        for (int ks = 0; ks < 64; ks += 32) { \
            int fo = ks ? (sw0 ^ 32) : sw0; \
            bf16x8 af[4], bfr[2]; \
            _Pragma("unroll") \
            for (int i = 0; i < 4; ++i) af[i]  = *(const bf16x8*)(&As[p][wr + 16 * i + fr][fo]); \
            _Pragma("unroll") \
            for (int j = 0; j < 2; ++j) bfr[j] = *(const bf16x8*)(&Bs[p][wc + 16 * j + fr][fo]); \
            _Pragma("unroll") \
            for (int i = 0; i < 4; ++i) \
            _Pragma("unroll") \
                for (int j = 0; j < 2; ++j) \
                    acc[i][j] = __builtin_amdgcn_mfma_f32_16x16x32_bf16(af[i], bfr[j], acc[i][j], 0, 0, 0); \
        } \
        __builtin_amdgcn_s_setprio(0); \
        BAR(); \
        if (t + 2 < (NT)) STAGE1(AB, LDA, BB, LDB, t + 2, p); \
    } }

// 8 waves: wave>>2 = M-half (64 rows), wave&3 = N-quarter (32 cols)
#define TILE_IDS() \
    int tid = threadIdx.x; \
    int lane = tid & 63, wave = tid >> 6; \
    int wr = (wave >> 2) * 64, wc = (wave & 3) * 32; \
    int fr = lane & 15; \
    int srow = tid >> 3, scol = (tid & 7) * 8; \
    int scolg = (((tid & 7) ^ (srow & 7)) * 8); \
    int sw0 = (((lane >> 4) ^ (fr & 7)) * 8)

// ---------------- prep: x->bf16 + 3 weight transposes (256 threads) ----------------

__global__ __launch_bounds__(256) void prep(
    const float* __restrict__ x, const float* __restrict__ Wq,
    const float* __restrict__ Wk, const float* __restrict__ Wv,
    unsigned short* __restrict__ x_bf, unsigned short* __restrict__ Wqk_t,
    unsigned short* __restrict__ Wv_t)
{
    int bid = blockIdx.x, tid = threadIdx.x;
    if (bid < 8192) {           // convert x: 8192*256 threads * 4 elems
        int i = bid * 256 + tid;
        f32x4 v = ((const f32x4*)x)[i];
        u16x4 o;
        o[0] = f2bf(v[0]); o[1] = f2bf(v[1]); o[2] = f2bf(v[2]); o[3] = f2bf(v[3]);
        ((u16x4*)x_bf)[i] = o;
        return;
    }
    // transpose-convert W[K=1024][N] -> Wt[N][1024], scaled
    const float* W; unsigned short* Wt; int N, lb; float scale;
    if (bid < 8448)      { W = Wq; Wt = Wqk_t;              N = 256;  lb = bid - 8192; scale = 1.f / 16.f; }
    else if (bid < 8704) { W = Wk; Wt = Wqk_t + 256 * 1024; N = 256;  lb = bid - 8448; scale = 1.f; }
    else                 { W = Wv; Wt = Wv_t;               N = 1024; lb = bid - 8704; scale = 1.f; }
    int nb = N >> 5;
    int n0 = (lb % nb) * 32, k0 = (lb / nb) * 32;
    int tx = tid & 31, ty = tid >> 5;   // 32 x 8
    __shared__ float tile[32][33];
#pragma unroll
    for (int r = 0; r < 4; ++r)
        tile[ty + 8 * r][tx] = W[(size_t)(k0 + ty + 8 * r) * N + n0 + tx];
    __syncthreads();
#pragma unroll
    for (int r = 0; r < 4; ++r)
        Wt[(size_t)(n0 + ty + 8 * r) * 1024 + k0 + tx] = f2bf(tile[tx][ty + 8 * r] * scale);
}

// ---------------- qkvt: Vt GEMM (0..511) + QK GEMM (512..767) ----------------

__global__ __launch_bounds__(512) void gemm_qkvt(
    const unsigned short* __restrict__ x_bf,
    const unsigned short* __restrict__ Wqk_t,
    const unsigned short* __restrict__ Wv_t,
    unsigned short* __restrict__ QK_bf,
    unsigned short* __restrict__ Vt_bf)
{
    int bid = blockIdx.x;
    const unsigned short *A, *B; unsigned short* C; int ldc, m0, n0;
    if (bid < 512) {
        A = Wv_t; B = x_bf; C = Vt_bf; ldc = 8192;
        m0 = (bid >> 6) * 128; n0 = (bid & 63) * 128;
    } else {
        int b2 = bid - 512;
        A = x_bf; B = Wqk_t; C = QK_bf; ldc = 512;
        m0 = (b2 >> 2) * 128; n0 = (b2 & 3) * 128;
    }
    __shared__ __align__(16) unsigned short As[2][128][64];
    __shared__ __align__(16) unsigned short Bs[2][128][64];
    TILE_IDS();
    f32x4 acc[4][2] = {};
    const unsigned short* Ab = A + (size_t)(m0 + srow) * 1024 + scolg;
    const unsigned short* Bb = B + (size_t)(n0 + srow) * 1024 + scolg;
    PIPE_MFMA(Ab, 1024, Bb, 1024, 16);
#pragma unroll
    for (int i = 0; i < 4; ++i)
#pragma unroll
        for (int j = 0; j < 2; ++j)
#pragma unroll
            for (int r = 0; r < 4; ++r)
                C[(size_t)(m0 + wr + 16 * i + (lane >> 4) * 4 + r) * ldc
                  + n0 + wc + 16 * j + fr] = f2bf(acc[i][j][r]);
}

// ---------------- scores: E = exp(Q Kt^T) bf16 + partial row sums ----------------
// Live (causal) tiles only: 544 blocks, XCD-bijective swizzle (544 = 8*68).

__global__ __launch_bounds__(512) void scores_e(
    const unsigned short* __restrict__ QK, unsigned short* __restrict__ Ebf,
    float* __restrict__ partials)
{
    int lin = blockIdx.x;                     // 0..543
    int swz = (lin & 7) * 68 + (lin >> 3);
    int b = swz / 136, t = swz - b * 136;
    int y = (int)floorf((sqrtf(8.f * (float)t + 1.f) - 1.f) * 0.5f);
    if ((y + 1) * (y + 2) / 2 <= t) ++y;
    if (y * (y + 1) / 2 > t) --y;
    int x = t - y * (y + 1) / 2;
    int m0 = y * 128, n0 = x * 128;

    const unsigned short* A  = QK + (size_t)b * 2048 * 512;
    const unsigned short* Bt = A + 256;
    unsigned short* Eb = Ebf + (size_t)b * 2048 * 2048;

    __shared__ __align__(16) unsigned short As[2][128][64];
    __shared__ __align__(16) unsigned short Bs[2][128][64];
    __shared__ float rowsum4[4][128];
    TILE_IDS();
    f32x4 acc[4][2] = {};
    const unsigned short* Ab = A  + (size_t)(m0 + srow) * 512 + scolg;
    const unsigned short* Bb = Bt + (size_t)(n0 + srow) * 512 + scolg;
    PIPE_MFMA(Ab, 512, Bb, 512, 4);

    // exp + mask + bf16 store + per-row partial sums (4 col-quarter waves/row)
#pragma unroll
    for (int i = 0; i < 4; ++i)
#pragma unroll
        for (int r = 0; r < 4; ++r) {
            int rloc = wr + 16 * i + (lane >> 4) * 4 + r;
            int q = m0 + rloc;
            float s = 0.f;
#pragma unroll
            for (int j = 0; j < 2; ++j) {
                int k = n0 + wc + 16 * j + fr;
                float e = (k <= q) ? __expf(acc[i][j][r]) : 0.f;
                Eb[(size_t)q * 2048 + k] = f2bf(e);
                s += e;
            }
            s += __shfl_xor(s, 1, 64); s += __shfl_xor(s, 2, 64);
            s += __shfl_xor(s, 4, 64); s += __shfl_xor(s, 8, 64);
            if (fr == 0) rowsum4[wave & 3][rloc] = s;
        }
    __syncthreads();
    if (tid < 128)
        partials[((size_t)b * 2048 + m0 + tid) * 16 + x] =
            rowsum4[0][tid] + rowsum4[1][tid] + rowsum4[2][tid] + rowsum4[3][tid];
}

// ---------------- pv_fin: PV GEMM (0..511) + W finalize (512..1535) ----------------

__global__ __launch_bounds__(512) void pv_fin(
    const unsigned short* __restrict__ E, const unsigned short* __restrict__ Vt,
    const float* __restrict__ partials, float* __restrict__ O,
    float* __restrict__ W)
{
    int bid = blockIdx.x;
    __shared__ __align__(16) unsigned short As[2][128][64];
    __shared__ __align__(16) unsigned short Bs[2][128][64];
    __shared__ float invsh[128];

    if (bid < 512) {
        // PV: O = (E @ V) * inv, causal k-limit, XCD-balanced decode
        int j   = bid & 7;
        int idx = bid >> 3;
        int x   = idx & 7;
        int h   = idx >> 3;
        int b   = h >> 1;
        int y   = (h & 1) ? j : 15 - j;   // row tile (balanced causal work)

        int m0 = y * 128, n0 = x * 128;
        const unsigned short* Pb = E + (size_t)b * 2048 * 2048;
        const unsigned short* Bt = Vt + (size_t)b * 2048;   // ldb = 8192
        float* Ob = O + (size_t)b * 2048 * 1024;
        int nt = (y + 1) * 2;

        TILE_IDS();
        f32x4 acc[4][2] = {};

        if (tid < 128) {
            const float* pp = partials + ((size_t)b * 2048 + m0 + tid) * 16;
            float s = 0.f;
            for (int i = 0; i <= y; ++i) s += pp[i];
            invsh[tid] = 1.f / s;
        }

        const unsigned short* Ab = Pb + (size_t)(m0 + srow) * 2048 + scolg;
        const unsigned short* Bb = Bt + (size_t)(n0 + srow) * 8192 + scolg;
        PIPE_MFMA(Ab, 2048, Bb, 8192, nt);
#pragma unroll
        for (int i = 0; i < 4; ++i)
#pragma unroll
            for (int r = 0; r < 4; ++r) {
                int rloc = wr + 16 * i + (lane >> 4) * 4 + r;
                float iv = invsh[rloc];
#pragma unroll
                for (int jj = 0; jj < 2; ++jj)
                    __builtin_nontemporal_store(acc[i][jj][r] * iv,
                        &Ob[(size_t)(m0 + rloc) * 1024 + n0 + wc + 16 * jj + fr]);
            }
        return;
    }

    // finalize: 8 rows/block, one row/wave; full 2048-col write (zeros above diag)
    int tid = threadIdx.x;
    int wave = tid >> 6, lane = tid & 63;
    int r = (bid - 512) * 8 + wave;       // 0..8191
    int q = r & 2047;
    float p = (lane < 16 && lane <= (q >> 7)) ? partials[(size_t)r * 16 + lane] : 0.f;
    p += __shfl_xor(p, 1, 64); p += __shfl_xor(p, 2, 64);
    p += __shfl_xor(p, 4, 64); p += __shfl_xor(p, 8, 64);
    float iv = 1.f / __shfl(p, 0, 64);
    const unsigned short* er = E + (size_t)r * 2048;
    float* wrow = W + (size_t)r * 2048;
#pragma unroll
    for (int cc = 0; cc < 4; ++cc) {
        int c0 = lane * 8 + cc * 512;
        f32x4 o0 = {}, o1 = {};
        if (c0 <= q) {   // masked entries within a live chunk are exact bf16 zeros
            bf16x8 e = *(const bf16x8*)(er + c0);
#pragma unroll
            for (int jj = 0; jj < 4; ++jj) {
                o0[jj] = bf2f((unsigned short)e[jj]) * iv;
                o1[jj] = bf2f((unsigned short)e[jj + 4]) * iv;
            }
        }
        __builtin_nontemporal_store(o0, (f32x4*)(wrow + c0));
        __builtin_nontemporal_store(o1, (f32x4*)(wrow + c0) + 1);
    }
}

// ---------------- launcher ----------------

extern "C" void kernel_launch(void* const* d_in, const int* in_sizes, int n_in,
                              void* d_out, int out_size, void* d_ws, size_t ws_size,
                              hipStream_t stream) {
    (void)in_sizes; (void)n_in; (void)out_size; (void)ws_size;
    const float* x  = (const float*)d_in[0];
    const float* Wq = (const float*)d_in[1];
    const float* Wk = (const float*)d_in[2];
    const float* Wv = (const float*)d_in[3];
    const int B = 4, T = 2048, D = 1024;
    const int M = B * T;  // 8192

    char* ws = (char*)d_ws;
    size_t off = 0;
    auto alloc = [&](size_t bytes) {
        void* p = ws + off; off += (bytes + 255) & ~(size_t)255; return p;
    };
    unsigned short* x_bf  = (unsigned short*)alloc((size_t)M * D * 2);
    unsigned short* Wqk_t = (unsigned short*)alloc((size_t)512 * D * 2);
    unsigned short* Wv_t  = (unsigned short*)alloc((size_t)D * D * 2);
    unsigned short* QK_bf = (unsigned short*)alloc((size_t)M * 512 * 2);
    unsigned short* Vt_bf = (unsigned short*)alloc((size_t)D * M * 2);
    unsigned short* E_bf  = (unsigned short*)alloc((size_t)M * T * 2);
    float*          parts = (float*)alloc((size_t)M * 16 * 4);

    float* outO = (float*)d_out;                       // [4][2048][1024]
    float* outW = (float*)d_out + (size_t)M * D;       // [4][2048][2048]

    // 1. prep: x->bf16 + 3 weight transposes
    prep<<<dim3(8192 + 256 + 256 + 1024), 256, 0, stream>>>(
        x, Wq, Wk, Wv, x_bf, Wqk_t, Wv_t);

    // 2. Vt GEMM + QK GEMM merged (768 blocks)
    gemm_qkvt<<<dim3(768), 512, 0, stream>>>(x_bf, Wqk_t, Wv_t, QK_bf, Vt_bf);

    // 3. scores -> bf16 E (unnormalized) + partial row sums (live tiles only)
    scores_e<<<dim3(544), 512, 0, stream>>>(QK_bf, E_bf, parts);

    // 4. PV GEMM + full-row W finalize (non-temporal output streams)
    pv_fin<<<dim3(512 + 1024), 512, 0, stream>>>(E_bf, Vt_bf, parts, outO, outW);
}

// Round 12
// 104.765 us; speedup vs baseline: 1.1309x; 1.1309x over previous
//
#include <hip/hip_runtime.h>

// CausalSelfAttention: B=4, T=2048, D=1024, DA=256, fp32 in/out.
// 4 launches: prep -> qkvt (Vt GEMM + QK GEMM) -> scores (bf16 E + partials)
// -> pv_fin (PV GEMM + W finalize). MFMA kernels: 128x128 tiles, 512 threads
// (8 waves 2Mx4N -> 16 waves/CU at 2 blocks/CU), T4 counted-vmcnt 2-buffer
// global_load_lds pipeline, T2 source-swizzled LDS (linear dest, XOR read).
// [R11 lesson: setprio hurts (lockstep barriers), NT stores hurt (W stream).]

typedef short bf16x8 __attribute__((ext_vector_type(8)));   // 8 bf16 in 4 VGPRs
typedef float f32x4  __attribute__((ext_vector_type(4)));
typedef unsigned int  u32x4 __attribute__((ext_vector_type(4)));
typedef unsigned short u16x4 __attribute__((ext_vector_type(4)));

static __device__ __forceinline__ unsigned short f2bf(float f) {
    union { float f; unsigned int u; } v; v.f = f;
    unsigned int u = v.u;
    return (unsigned short)((u + 0x7FFFu + ((u >> 16) & 1u)) >> 16);  // RNE
}
static __device__ __forceinline__ float bf2f(unsigned short h) {
    union { unsigned int u; float f; } v; v.u = ((unsigned int)h) << 16; return v.f;
}

// async global->LDS, 16B per lane; LDS dest must be wave-linear (lane*16).
#define GLL(g, l) __builtin_amdgcn_global_load_lds( \
    (const __attribute__((address_space(1))) void*)(g), \
    (__attribute__((address_space(3))) void*)(l), 16, 0, 0)

#define BAR() __builtin_amdgcn_s_barrier()
#define VM4() asm volatile("s_waitcnt vmcnt(4)" ::: "memory")
#define VM0() asm volatile("s_waitcnt vmcnt(0)" ::: "memory")

// ---- 512-thread pipeline: 128x128 tile, BK=64, 4 GLL/step (2 per matrix) ----

#define STAGE1(AB, LDA, BB, LDB, t, p) { \
    const unsigned short* Ap_ = (AB) + (size_t)(t) * 64; \
    const unsigned short* Bp_ = (BB) + (size_t)(t) * 64; \
    _Pragma("unroll") \
    for (int i_ = 0; i_ < 2; ++i_) { \
        GLL(Ap_ + (size_t)64 * i_ * (LDA), &As[p][srow + 64 * i_][scol]); \
        GLL(Bp_ + (size_t)64 * i_ * (LDB), &Bs[p][srow + 64 * i_][scol]); \
    } }

#define PIPE_MFMA(AB, LDA, BB, LDB, NT) { \
    STAGE1(AB, LDA, BB, LDB, 0, 0); \
    STAGE1(AB, LDA, BB, LDB, 1, 1); \
    for (int t = 0; t < (NT); ++t) { \
        int p = t & 1; \
        if (t + 1 < (NT)) VM4(); else VM0(); \
        BAR(); \
        _Pragma("unroll") \
        for (int ks = 0; ks < 64; ks += 32) { \
            int fo = ks ? (sw0 ^ 32) : sw0; \
            bf16x8 af[4], bfr[2]; \
            _Pragma("unroll") \
            for (int i = 0; i < 4; ++i) af[i]  = *(const bf16x8*)(&As[p][wr + 16 * i + fr][fo]); \
            _Pragma("unroll") \
            for (int j = 0; j < 2; ++j) bfr[j] = *(const bf16x8*)(&Bs[p][wc + 16 * j + fr][fo]); \
            _Pragma("unroll") \
            for (int i = 0; i < 4; ++i) \
            _Pragma("unroll") \
                for (int j = 0; j < 2; ++j) \
                    acc[i][j] = __builtin_amdgcn_mfma_f32_16x16x32_bf16(af[i], bfr[j], acc[i][j], 0, 0, 0); \
        } \
        BAR(); \
        if (t + 2 < (NT)) STAGE1(AB, LDA, BB, LDB, t + 2, p); \
    } }

// 8 waves: wave>>2 = M-half (64 rows), wave&3 = N-quarter (32 cols)
#define TILE_IDS() \
    int tid = threadIdx.x; \
    int lane = tid & 63, wave = tid >> 6; \
    int wr = (wave >> 2) * 64, wc = (wave & 3) * 32; \
    int fr = lane & 15; \
    int srow = tid >> 3, scol = (tid & 7) * 8; \
    int scolg = (((tid & 7) ^ (srow & 7)) * 8); \
    int sw0 = (((lane >> 4) ^ (fr & 7)) * 8)

// ---------------- prep: x->bf16 + 3 weight transposes (256 threads) ----------------

__global__ __launch_bounds__(256) void prep(
    const float* __restrict__ x, const float* __restrict__ Wq,
    const float* __restrict__ Wk, const float* __restrict__ Wv,
    unsigned short* __restrict__ x_bf, unsigned short* __restrict__ Wqk_t,
    unsigned short* __restrict__ Wv_t)
{
    int bid = blockIdx.x, tid = threadIdx.x;
    if (bid < 8192) {           // convert x: 8192*256 threads * 4 elems
        int i = bid * 256 + tid;
        f32x4 v = ((const f32x4*)x)[i];
        u16x4 o;
        o[0] = f2bf(v[0]); o[1] = f2bf(v[1]); o[2] = f2bf(v[2]); o[3] = f2bf(v[3]);
        ((u16x4*)x_bf)[i] = o;
        return;
    }
    // transpose-convert W[K=1024][N] -> Wt[N][1024], scaled
    const float* W; unsigned short* Wt; int N, lb; float scale;
    if (bid < 8448)      { W = Wq; Wt = Wqk_t;              N = 256;  lb = bid - 8192; scale = 1.f / 16.f; }
    else if (bid < 8704) { W = Wk; Wt = Wqk_t + 256 * 1024; N = 256;  lb = bid - 8448; scale = 1.f; }
    else                 { W = Wv; Wt = Wv_t;               N = 1024; lb = bid - 8704; scale = 1.f; }
    int nb = N >> 5;
    int n0 = (lb % nb) * 32, k0 = (lb / nb) * 32;
    int tx = tid & 31, ty = tid >> 5;   // 32 x 8
    __shared__ float tile[32][33];
#pragma unroll
    for (int r = 0; r < 4; ++r)
        tile[ty + 8 * r][tx] = W[(size_t)(k0 + ty + 8 * r) * N + n0 + tx];
    __syncthreads();
#pragma unroll
    for (int r = 0; r < 4; ++r)
        Wt[(size_t)(n0 + ty + 8 * r) * 1024 + k0 + tx] = f2bf(tile[tx][ty + 8 * r] * scale);
}

// ---------------- qkvt: Vt GEMM (0..511) + QK GEMM (512..767) ----------------

__global__ __launch_bounds__(512) void gemm_qkvt(
    const unsigned short* __restrict__ x_bf,
    const unsigned short* __restrict__ Wqk_t,
    const unsigned short* __restrict__ Wv_t,
    unsigned short* __restrict__ QK_bf,
    unsigned short* __restrict__ Vt_bf)
{
    int bid = blockIdx.x;
    const unsigned short *A, *B; unsigned short* C; int ldc, m0, n0;
    if (bid < 512) {
        A = Wv_t; B = x_bf; C = Vt_bf; ldc = 8192;
        m0 = (bid >> 6) * 128; n0 = (bid & 63) * 128;
    } else {
        int b2 = bid - 512;
        A = x_bf; B = Wqk_t; C = QK_bf; ldc = 512;
        m0 = (b2 >> 2) * 128; n0 = (b2 & 3) * 128;
    }
    __shared__ __align__(16) unsigned short As[2][128][64];
    __shared__ __align__(16) unsigned short Bs[2][128][64];
    TILE_IDS();
    f32x4 acc[4][2] = {};
    const unsigned short* Ab = A + (size_t)(m0 + srow) * 1024 + scolg;
    const unsigned short* Bb = B + (size_t)(n0 + srow) * 1024 + scolg;
    PIPE_MFMA(Ab, 1024, Bb, 1024, 16);
#pragma unroll
    for (int i = 0; i < 4; ++i)
#pragma unroll
        for (int j = 0; j < 2; ++j)
#pragma unroll
            for (int r = 0; r < 4; ++r)
                C[(size_t)(m0 + wr + 16 * i + (lane >> 4) * 4 + r) * ldc
                  + n0 + wc + 16 * j + fr] = f2bf(acc[i][j][r]);
}

// ---------------- scores: E = exp(Q Kt^T) bf16 + partial row sums ----------------
// Live (causal) tiles only: 544 blocks, XCD-bijective swizzle (544 = 8*68).

__global__ __launch_bounds__(512) void scores_e(
    const unsigned short* __restrict__ QK, unsigned short* __restrict__ Ebf,
    float* __restrict__ partials)
{
    int lin = blockIdx.x;                     // 0..543
    int swz = (lin & 7) * 68 + (lin >> 3);
    int b = swz / 136, t = swz - b * 136;
    int y = (int)floorf((sqrtf(8.f * (float)t + 1.f) - 1.f) * 0.5f);
    if ((y + 1) * (y + 2) / 2 <= t) ++y;
    if (y * (y + 1) / 2 > t) --y;
    int x = t - y * (y + 1) / 2;
    int m0 = y * 128, n0 = x * 128;

    const unsigned short* A  = QK + (size_t)b * 2048 * 512;
    const unsigned short* Bt = A + 256;
    unsigned short* Eb = Ebf + (size_t)b * 2048 * 2048;

    __shared__ __align__(16) unsigned short As[2][128][64];
    __shared__ __align__(16) unsigned short Bs[2][128][64];
    __shared__ float rowsum4[4][128];
    TILE_IDS();
    f32x4 acc[4][2] = {};
    const unsigned short* Ab = A  + (size_t)(m0 + srow) * 512 + scolg;
    const unsigned short* Bb = Bt + (size_t)(n0 + srow) * 512 + scolg;
    PIPE_MFMA(Ab, 512, Bb, 512, 4);

    // exp + mask + bf16 store + per-row partial sums (4 col-quarter waves/row)
#pragma unroll
    for (int i = 0; i < 4; ++i)
#pragma unroll
        for (int r = 0; r < 4; ++r) {
            int rloc = wr + 16 * i + (lane >> 4) * 4 + r;
            int q = m0 + rloc;
            float s = 0.f;
#pragma unroll
            for (int j = 0; j < 2; ++j) {
                int k = n0 + wc + 16 * j + fr;
                float e = (k <= q) ? __expf(acc[i][j][r]) : 0.f;
                Eb[(size_t)q * 2048 + k] = f2bf(e);
                s += e;
            }
            s += __shfl_xor(s, 1, 64); s += __shfl_xor(s, 2, 64);
            s += __shfl_xor(s, 4, 64); s += __shfl_xor(s, 8, 64);
            if (fr == 0) rowsum4[wave & 3][rloc] = s;
        }
    __syncthreads();
    if (tid < 128)
        partials[((size_t)b * 2048 + m0 + tid) * 16 + x] =
            rowsum4[0][tid] + rowsum4[1][tid] + rowsum4[2][tid] + rowsum4[3][tid];
}

// ---------------- pv_fin: PV GEMM (0..511) + W finalize (512..1535) ----------------

__global__ __launch_bounds__(512) void pv_fin(
    const unsigned short* __restrict__ E, const unsigned short* __restrict__ Vt,
    const float* __restrict__ partials, float* __restrict__ O,
    float* __restrict__ W)
{
    int bid = blockIdx.x;
    __shared__ __align__(16) unsigned short As[2][128][64];
    __shared__ __align__(16) unsigned short Bs[2][128][64];
    __shared__ float invsh[128];

    if (bid < 512) {
        // PV: O = (E @ V) * inv, causal k-limit, XCD-balanced decode
        int j   = bid & 7;
        int idx = bid >> 3;
        int x   = idx & 7;
        int h   = idx >> 3;
        int b   = h >> 1;
        int y   = (h & 1) ? j : 15 - j;   // row tile (balanced causal work)

        int m0 = y * 128, n0 = x * 128;
        const unsigned short* Pb = E + (size_t)b * 2048 * 2048;
        const unsigned short* Bt = Vt + (size_t)b * 2048;   // ldb = 8192
        float* Ob = O + (size_t)b * 2048 * 1024;
        int nt = (y + 1) * 2;

        TILE_IDS();
        f32x4 acc[4][2] = {};

        if (tid < 128) {
            const float* pp = partials + ((size_t)b * 2048 + m0 + tid) * 16;
            float s = 0.f;
            for (int i = 0; i <= y; ++i) s += pp[i];
            invsh[tid] = 1.f / s;
        }

        const unsigned short* Ab = Pb + (size_t)(m0 + srow) * 2048 + scolg;
        const unsigned short* Bb = Bt + (size_t)(n0 + srow) * 8192 + scolg;
        PIPE_MFMA(Ab, 2048, Bb, 8192, nt);
#pragma unroll
        for (int i = 0; i < 4; ++i)
#pragma unroll
            for (int r = 0; r < 4; ++r) {
                int rloc = wr + 16 * i + (lane >> 4) * 4 + r;
                float iv = invsh[rloc];
#pragma unroll
                for (int jj = 0; jj < 2; ++jj)
                    Ob[(size_t)(m0 + rloc) * 1024 + n0 + wc + 16 * jj + fr] = acc[i][jj][r] * iv;
            }
        return;
    }

    // finalize: 8 rows/block, one row/wave; full 2048-col write (zeros above diag)
    int tid = threadIdx.x;
    int wave = tid >> 6, lane = tid & 63;
    int r = (bid - 512) * 8 + wave;       // 0..8191
    int q = r & 2047;
    float p = (lane < 16 && lane <= (q >> 7)) ? partials[(size_t)r * 16 + lane] : 0.f;
    p += __shfl_xor(p, 1, 64); p += __shfl_xor(p, 2, 64);
    p += __shfl_xor(p, 4, 64); p += __shfl_xor(p, 8, 64);
    float iv = 1.f / __shfl(p, 0, 64);
    const unsigned short* er = E + (size_t)r * 2048;
    float* wrow = W + (size_t)r * 2048;
#pragma unroll
    for (int cc = 0; cc < 4; ++cc) {
        int c0 = lane * 8 + cc * 512;
        f32x4 o0 = {}, o1 = {};
        if (c0 <= q) {   // masked entries within a live chunk are exact bf16 zeros
            bf16x8 e = *(const bf16x8*)(er + c0);
#pragma unroll
            for (int jj = 0; jj < 4; ++jj) {
                o0[jj] = bf2f((unsigned short)e[jj]) * iv;
                o1[jj] = bf2f((unsigned short)e[jj + 4]) * iv;
            }
        }
        *((f32x4*)(wrow + c0)) = o0;
        *((f32x4*)(wrow + c0) + 1) = o1;
    }
}

// ---------------- launcher ----------------

extern "C" void kernel_launch(void* const* d_in, const int* in_sizes, int n_in,
                              void* d_out, int out_size, void* d_ws, size_t ws_size,
                              hipStream_t stream) {
    (void)in_sizes; (void)n_in; (void)out_size; (void)ws_size;
    const float* x  = (const float*)d_in[0];
    const float* Wq = (const float*)d_in[1];
    const float* Wk = (const float*)d_in[2];
    const float* Wv = (const float*)d_in[3];
    const int B = 4, T = 2048, D = 1024;
    const int M = B * T;  // 8192

    char* ws = (char*)d_ws;
    size_t off = 0;
    auto alloc = [&](size_t bytes) {
        void* p = ws + off; off += (bytes + 255) & ~(size_t)255; return p;
    };
    unsigned short* x_bf  = (unsigned short*)alloc((size_t)M * D * 2);
    unsigned short* Wqk_t = (unsigned short*)alloc((size_t)512 * D * 2);
    unsigned short* Wv_t  = (unsigned short*)alloc((size_t)D * D * 2);
    unsigned short* QK_bf = (unsigned short*)alloc((size_t)M * 512 * 2);
    unsigned short* Vt_bf = (unsigned short*)alloc((size_t)D * M * 2);
    unsigned short* E_bf  = (unsigned short*)alloc((size_t)M * T * 2);
    float*          parts = (float*)alloc((size_t)M * 16 * 4);

    float* outO = (float*)d_out;                       // [4][2048][1024]
    float* outW = (float*)d_out + (size_t)M * D;       // [4][2048][2048]

    // 1. prep: x->bf16 + 3 weight transposes
    prep<<<dim3(8192 + 256 + 256 + 1024), 256, 0, stream>>>(
        x, Wq, Wk, Wv, x_bf, Wqk_t, Wv_t);

    // 2. Vt GEMM + QK GEMM merged (768 blocks)
    gemm_qkvt<<<dim3(768), 512, 0, stream>>>(x_bf, Wqk_t, Wv_t, QK_bf, Vt_bf);

    // 3. scores -> bf16 E (unnormalized) + partial row sums (live tiles only)
    scores_e<<<dim3(544), 512, 0, stream>>>(QK_bf, E_bf, parts);

    // 4. PV GEMM + full-row W finalize
    pv_fin<<<dim3(512 + 1024), 512, 0, stream>>>(E_bf, Vt_bf, parts, outO, outW);
}